// Round 1
// 530.174 us; speedup vs baseline: 1.1034x; 1.1034x over previous
//
#include <hip/hip_runtime.h>
#include <math.h>

#define NNODES 6000
#define NEDGES 192000
#define DIN 512
#define HDIM 128
#define ALPHA 1.0f
#define EOS 1e-10f
// Per-row edge-bucket capacity. Degree is Poisson(32) on a FIXED seed-0 input;
// P(any row > 256) is astronomically small. Overflow edges are dropped (never).
#define KMAX 256

static const size_t NN = (size_t)NNODES * (size_t)NNODES;

// ---------------------------------------------------------------------------
// Kernel 1: per-node scalar g[i] = dot(relu(feat[i] @ w_emb + b_emb), wv)
// where wv[h] = 0.5*(w_mlp[h] + w_mlp[H+h]).  8 nodes per block, 128 threads
// (thread = h index).  Feature rows staged in LDS; consumed via ds_read_b128
// (float4) — 4x fewer LDS issues than the previous per-element b32 reads.
// ---------------------------------------------------------------------------
__global__ __launch_bounds__(128) void embed_g_kernel(
    const float* __restrict__ feat, const float* __restrict__ w_emb,
    const float* __restrict__ b_emb, const float* __restrict__ w_mlp,
    float* __restrict__ g) {
  __shared__ float sf[8 * DIN];
  __shared__ float red[2][8];
  const int t = threadIdx.x;
  const int nb = blockIdx.x * 8;

  // stage 8 feature rows (contiguous: 4096 floats = 1024 float4)
  const float4* f4 = (const float4*)(feat + (size_t)nb * DIN);
  float4* s4 = (float4*)sf;
#pragma unroll
  for (int k = 0; k < 8; ++k) s4[k * 128 + t] = f4[k * 128 + t];
  __syncthreads();

  const int h = t;
  float acc[8];
  const float b = b_emb[h];
#pragma unroll
  for (int n = 0; n < 8; ++n) acc[n] = b;

  const float4* sf4 = (const float4*)sf;
#pragma unroll 2
  for (int d4 = 0; d4 < DIN / 4; ++d4) {
    const float w0 = w_emb[(d4 * 4 + 0) * HDIM + h];  // coalesced across h
    const float w1 = w_emb[(d4 * 4 + 1) * HDIM + h];
    const float w2 = w_emb[(d4 * 4 + 2) * HDIM + h];
    const float w3 = w_emb[(d4 * 4 + 3) * HDIM + h];
#pragma unroll
    for (int n = 0; n < 8; ++n) {
      const float4 f = sf4[n * (DIN / 4) + d4];  // LDS broadcast, b128
      acc[n] += f.x * w0;
      acc[n] += f.y * w1;
      acc[n] += f.z * w2;
      acc[n] += f.w * w3;
    }
  }

  const float wv = 0.5f * (w_mlp[h] + w_mlp[HDIM + h]);
  const int lane = t & 63, wave = t >> 6;
#pragma unroll
  for (int n = 0; n < 8; ++n) {
    float v = fmaxf(acc[n], 0.0f) * wv;
    for (int off = 32; off > 0; off >>= 1) v += __shfl_down(v, off, 64);
    if (lane == 0) red[wave][n] = v;
  }
  __syncthreads();
  if (t < 8) g[nb + t] = red[0][t] + red[1][t];
}

// ---------------------------------------------------------------------------
// Kernel 2: per-edge gate weights + row bucketing.  The per-row edge-id lists
// are stored at the START of each unnorm output row (reinterpreted as int) —
// they are consumed by K3/K5 before the paint pass overwrites them, and only
// the block that owns row r ever reads row r's list, so there is no
// cross-block ordering hazard.  Replaces the old 144-MB atomicMax winner
// array (whose zeroing + scattered RMW traffic dominated the edge passes).
// ---------------------------------------------------------------------------
__global__ __launch_bounds__(256) void edge_bucket_kernel(
    const int* __restrict__ edges, const float* __restrict__ g,
    const float* __restrict__ noise, const float* __restrict__ b_mlp,
    float* __restrict__ w_lp, float* __restrict__ w_hp,
    int* __restrict__ cnt, int* __restrict__ slots) {
  const int e = blockIdx.x * blockDim.x + threadIdx.x;
  if (e >= NEDGES) return;
  const int u = edges[e];
  const int v = edges[NEDGES + e];
  const float raw = g[u] + g[v] + b_mlp[0];
  const float x = noise[e] + raw;  // TEMP == 1.0
  const float wl = 1.0f / (1.0f + expf(-x));
  w_lp[e] = wl;
  w_hp[e] = 1.0f - wl;
  const int k = atomicAdd(&cnt[u], 1);  // 24-KB counter array, L2-resident
  if (k < KMAX) slots[(size_t)u * NNODES + k] = e;
}

// ---------------------------------------------------------------------------
// Kernel 3: per-row dedup (last-write-wins == max edge id, matching the JAX
// scatter-set semantics the previous winner-matrix scheme verified) + exact
// row-degree sums.  One wave per row, 4 rows per 256-thread block.  Rewrites
// each slot as packed (e<<14)|(v<<1)|win for the paint pass.
// ---------------------------------------------------------------------------
__global__ __launch_bounds__(256) void row_dedup_deg_kernel(
    const int* __restrict__ edges, const float* __restrict__ w_lp,
    const float* __restrict__ w_hp, const int* __restrict__ cnt,
    int* __restrict__ slots, float* __restrict__ deg_lp,
    float* __restrict__ deg_hp) {
  __shared__ int se[4][KMAX];
  __shared__ int sv[4][KMAX];
  __shared__ float sl[4][KMAX];
  __shared__ float sh[4][KMAX];
  const int wid = threadIdx.x >> 6;
  const int lane = threadIdx.x & 63;
  const int r = blockIdx.x * 4 + wid;  // grid = 1500 -> r always < NNODES

  int k = cnt[r];
  if (k > KMAX) k = KMAX;
  int* srow = slots + (size_t)r * NNODES;
  for (int i = lane; i < k; i += 64) {
    const int e = srow[i];
    se[wid][i] = e;
    sv[wid][i] = edges[NEDGES + e];
    sl[wid][i] = w_lp[e];
    sh[wid][i] = w_hp[e];
  }
  __syncthreads();  // also covers the (rare) cross-wave LDS visibility

  float suml = 0.0f, sumh = 0.0f;
  for (int i = lane; i < k; i += 64) {
    const int e = se[wid][i];
    const int v = sv[wid][i];
    int win = 1;
    for (int j = 0; j < k; ++j) {
      if (sv[wid][j] == v && se[wid][j] > e) { win = 0; break; }
    }
    if (win) {
      suml += sl[wid][i];
      sumh += sh[wid][i];
    }
    srow[i] = (e << 14) | (v << 1) | win;  // decode with unsigned >> 14
  }
  for (int off = 32; off > 0; off >>= 1) {
    suml += __shfl_down(suml, off, 64);
    sumh += __shfl_down(sumh, off, 64);
  }
  if (lane == 0) {
    deg_lp[r] = suml;  // +1 for eye added in node_inv
    deg_hp[r] = sumh;
  }
}

// ---------------------------------------------------------------------------
// Kernel 4: inverse sqrt degrees (+1 for eye).  Diagonals now written by the
// paint pass (no scattered RMW into cold adjacency lines).
// ---------------------------------------------------------------------------
__global__ __launch_bounds__(256) void node_inv_kernel(
    const float* __restrict__ deg_lp, const float* __restrict__ deg_hp,
    float* __restrict__ inv_lp, float* __restrict__ inv_hp) {
  const int i = blockIdx.x * blockDim.x + threadIdx.x;
  if (i >= NNODES) return;
  inv_lp[i] = 1.0f / (sqrtf(deg_lp[i] + 1.0f) + EOS);
  inv_hp[i] = 1.0f / (sqrtf(deg_hp[i] + 1.0f) + EOS);
}

// ---------------------------------------------------------------------------
// Kernel 5: row paint — writes every byte of adj_lp/adj_hp/unnorm exactly
// once.  Block r: (1) decode row r's slot list (lives at the head of unnorm
// row r), (2) barrier (drains the slot loads), (3) float4 zero-fill all three
// rows, (4) barrier, (5) override the ~32 edge cells + diagonal while the
// lines are still in L2.  Replaces memset(288MB)+memset(144MB)+3 scattered
// RMW passes with one streaming write pass (433 MB total, the HBM floor).
// ---------------------------------------------------------------------------
__global__ __launch_bounds__(256) void paint_kernel(
    const float* __restrict__ w_lp, const float* __restrict__ w_hp,
    const float* __restrict__ inv_lp, const float* __restrict__ inv_hp,
    const int* __restrict__ cnt, float* __restrict__ adj_lp,
    float* __restrict__ adj_hp, float* __restrict__ unnorm) {
  __shared__ int scol[KMAX];    // (v<<1)|win
  __shared__ float slp[KMAX];   // wl * il_u * il_v
  __shared__ float shp[KMAX];   // -ALPHA * wh * ih_u * ih_v
  __shared__ int has_self;      // any self-edge => mask[r][r] == 1
  __shared__ float sdiag[2];    // winning self-edge (wl, wh)

  const int t = threadIdx.x;
  const int r = blockIdx.x;
  int k = cnt[r];
  if (k > KMAX) k = KMAX;
  const float il = inv_lp[r];
  const float ih = inv_hp[r];

  float* lp_row = adj_lp + (size_t)r * NNODES;
  float* hp_row = adj_hp + (size_t)r * NNODES;
  float* un_row = unnorm + (size_t)r * NNODES;
  const int* srow = (const int*)un_row;  // packed slots from K3

  if (t == 0) {
    has_self = 0;
    sdiag[0] = 0.0f;
    sdiag[1] = 0.0f;
  }
  __syncthreads();

  if (t < k) {
    const int raw = srow[t];
    const int win = raw & 1;
    const int v = (raw >> 1) & 0x1FFF;
    const int e = (int)(((unsigned)raw) >> 14);
    const float wl = w_lp[e];
    const float wh = w_hp[e];
    scol[t] = (v << 1) | win;
    slp[t] = wl * il * inv_lp[v];
    shp[t] = -ALPHA * wh * ih * inv_hp[v];
    if (v == r) {
      has_self = 1;  // benign same-value race across dup self-edges
      if (win) {
        sdiag[0] = wl;  // unique writer: the winning self-edge
        sdiag[1] = wh;
      }
    }
  }
  __syncthreads();  // slot loads from un_row complete before zero-fill

  const float4 z = make_float4(0.0f, 0.0f, 0.0f, 0.0f);
  float4* lp4 = (float4*)lp_row;
  float4* hp4 = (float4*)hp_row;
  float4* un4 = (float4*)un_row;
  for (int c = t; c < NNODES / 4; c += 256) {
    lp4[c] = z;
    hp4[c] = z;
    un4[c] = z;
  }
  __syncthreads();  // zeros retired before overrides (vmcnt drained)

  if (t < k) {
    const int cw = scol[t];
    const int win = cw & 1;
    const int v = cw >> 1;
    un_row[v] = 1.0f;  // mask: every edge cell (dups write same value)
    if (win && v != r) {
      lp_row[v] = slp[t];
      hp_row[v] = shp[t];
    }
  }
  if (t == 0) {
    if (has_self) {
      lp_row[r] = (sdiag[0] + 1.0f) * il * il;
      hp_row[r] = 1.0f - (sdiag[1] + 1.0f) * ih * ih * ALPHA;
    } else {
      lp_row[r] = il * il;  // eye-only diagonal, normalized
      hp_row[r] = 1.0f;     // eye - 0 (mask = 0 on diag)
    }
  }
}

extern "C" void kernel_launch(void* const* d_in, const int* in_sizes, int n_in,
                              void* d_out, int out_size, void* d_ws,
                              size_t ws_size, hipStream_t stream) {
  const float* feat  = (const float*)d_in[0];
  const int*   edges = (const int*)d_in[1];
  const float* w_emb = (const float*)d_in[2];
  const float* b_emb = (const float*)d_in[3];
  const float* w_mlp = (const float*)d_in[4];
  const float* b_mlp = (const float*)d_in[5];
  const float* noise = (const float*)d_in[6];

  float* out    = (float*)d_out;
  float* adj_lp = out;                 // [N,N]
  float* adj_hp = out + NN;            // [N,N]
  float* w_lp   = out + 2 * NN;        // [E]
  float* w_hp   = w_lp + NEDGES;       // [E]
  float* unnorm = w_hp + NEDGES;       // [N,N] (heads double as slot lists)

  // workspace: 6 x 24 KB = 144 KB
  float* g      = (float*)d_ws;        // [N]
  float* deg_lp = g + NNODES;          // [N]
  float* deg_hp = deg_lp + NNODES;     // [N]
  float* inv_lp = deg_hp + NNODES;     // [N]
  float* inv_hp = inv_lp + NNODES;     // [N]
  int*   cnt    = (int*)(inv_hp + NNODES);  // [N]

  // Only 24 KB of zeroing remains (row counters). No big memsets: every byte
  // of the three N x N outputs is written exactly once by paint_kernel.
  hipMemsetAsync(cnt, 0, NNODES * sizeof(int), stream);

  embed_g_kernel<<<NNODES / 8, 128, 0, stream>>>(feat, w_emb, b_emb, w_mlp, g);

  edge_bucket_kernel<<<NEDGES / 256, 256, 0, stream>>>(
      edges, g, noise, b_mlp, w_lp, w_hp, cnt, (int*)unnorm);

  row_dedup_deg_kernel<<<NNODES / 4, 256, 0, stream>>>(
      edges, w_lp, w_hp, cnt, (int*)unnorm, deg_lp, deg_hp);

  node_inv_kernel<<<(NNODES + 255) / 256, 256, 0, stream>>>(
      deg_lp, deg_hp, inv_lp, inv_hp);

  paint_kernel<<<NNODES, 256, 0, stream>>>(w_lp, w_hp, inv_lp, inv_hp, cnt,
                                           adj_lp, adj_hp, unnorm);
}